// Round 1
// 296.748 us; speedup vs baseline: 1.0921x; 1.0921x over previous
//
#include <hip/hip_runtime.h>
#include <math.h>

constexpr int D  = 64;
constexpr int T  = 200;
constexpr int H0 = 80;
constexpr int H1 = 40;
constexpr int BLOCK = 256;
constexpr float NEG_INF_V = -4294967295.0f;

typedef short short8 __attribute__((ext_vector_type(8)));
typedef float f32x4 __attribute__((ext_vector_type(4)));

// Split fp32 into two bf16 (RNE): x ~= hi + lo, |x-hi-lo| <= 2^-18|x|.
__device__ inline void split_bf16(float x, unsigned short& hi, unsigned short& lo) {
    union { float f; unsigned u; } a; a.f = x;
    unsigned r = a.u + 0x7FFF + ((a.u >> 16) & 1);
    hi = (unsigned short)(r >> 16);
    union { unsigned u; float f; } h; h.u = (unsigned)hi << 16;
    union { float f; unsigned u; } bvu; bvu.f = x - h.f;
    unsigned r2 = bvu.u + 0x7FFF + ((bvu.u >> 16) & 1);
    lo = (unsigned short)(r2 >> 16);
}

// ============ Fully fused kernel ============
// One block per batch b, 4 waves, 2 blocks/CU (LDS 63.5 KB).
// Phase 0 (per block): fold weff[kk][n] = W0[64+kk][n]-W0[128+kk][n]+q_kk*W0[192+kk][n]
//   and W1 (padded 96x48) into split-bf16 MFMA B-fragments in LDS, coalesced
//   linear reads of W0/W1. biasq[h] = b0[h] + sum_d q_d*(W0[d][h]+W0[128+d][h]).
//   First k-tile loads are issued BEFORE the fold so HBM latency hides under it.
// Phase 1: wave w owns M-tiles {w, w+4, ...} of 13 (M=200 pad 208), k rows
//   prefetched one tile ahead. Layer1: 5 fully-unrolled N-tiles (independent
//   acc chains) of 6 split-MFMAs each, B-frags from LDS (conflict-free b128).
//   h0 -> per-wave LDS tile [16][80] (split bf16), layer2 A-frags read back
//   (k2-pad 80->96 handled by predicated zero frags; W1 B-frag pad is zero so
//   A*0 contributes nothing for real columns). Head reduced via shfl_xor.
//   No block barriers inside the mt loop (same-wave LDS, lgkmcnt(0) only).
// Phase 2: softmax over T + out[b,d] = sum_t w_t v[b,t,d].
__global__ __launch_bounds__(BLOCK, 2) void attn_fused(
    const float* __restrict__ q, const float* __restrict__ k,
    const float* __restrict__ v, const float* __restrict__ W0,
    const float* __restrict__ b0, const float* __restrict__ a0,
    const float* __restrict__ W1, const float* __restrict__ b1,
    const float* __restrict__ a1, const float* __restrict__ Wo,
    const int* __restrict__ mask, float* __restrict__ out)
{
    __shared__ unsigned short s_wfHi[5120];       // 10 KB  weff B-frags hi
    __shared__ unsigned short s_wfLo[5120];       // 10 KB
    __shared__ unsigned short s_w1Hi[4608];       // 9 KB   W1 B-frags hi
    __shared__ unsigned short s_w1Lo[4608];       // 9 KB
    __shared__ unsigned short s_h0hi[4][16 * 80]; // 10 KB  per-wave h0 tiles
    __shared__ unsigned short s_h0lo[4][16 * 80]; // 10 KB
    __shared__ float s_logits[208];
    __shared__ float s_biasq[H0];
    __shared__ float s_a0[H0];
    __shared__ float s_b1p[48], s_a1p[48], s_Wop[48];
    __shared__ float s_w[BLOCK];
    __shared__ float s_red[8];
    __shared__ float s_part[4][D];

    const int tid  = threadIdx.x;
    const int b    = blockIdx.x;
    const int wv   = tid >> 6;
    const int lane = tid & 63;
    const int l16  = lane & 15;
    const int quad = lane >> 4;
    const float* qb = q + (size_t)b * D;

    // ---- early global issues: mask + first k tile (latency hides under fold)
    const int mval = (tid < T) ? mask[(size_t)b * T + tid] : 0;
    float4 kc[4];
    {
        int row = wv * 16 + l16; if (row > T - 1) row = T - 1;
        const float* kr = k + ((size_t)b * T + row) * D + quad * 8;
        kc[0] = *(const float4*)(kr);
        kc[1] = *(const float4*)(kr + 4);
        kc[2] = *(const float4*)(kr + 32);
        kc[3] = *(const float4*)(kr + 36);
    }

    // ---- Phase 0: fold weff into LDS B-frags (coalesced W0 reads) ----
    const float* Wk = W0 + 64 * H0;
    const float* Wd = W0 + 128 * H0;
    const float* Wp = W0 + 192 * H0;
    #pragma unroll 4
    for (int it = 0; it < 20; ++it) {
        const int e  = it * 256 + tid;            // e in [0, 5120)
        const int kk = e / 80, n = e - kk * 80;
        const float w = Wk[e] - Wd[e] + qb[kk] * Wp[e];
        unsigned short h, l; split_bf16(w, h, l);
        const int off = (((kk >> 5) * 5 + (n >> 4)) << 9)
                      + ((((kk >> 3) & 3) * 16 + (n & 15)) << 3) + (kk & 7);
        s_wfHi[off] = h; s_wfLo[off] = l;
    }
    // W1 frags, padded 96x48 with zeros
    #pragma unroll 4
    for (int it = 0; it < 18; ++it) {
        const int e  = it * 256 + tid;            // e in [0, 4608)
        const int k2 = e / 48, n = e - k2 * 48;
        const float w = (k2 < H0 && n < H1) ? W1[k2 * H1 + n] : 0.0f;
        unsigned short h, l; split_bf16(w, h, l);
        const int off = (((k2 >> 5) * 3 + (n >> 4)) << 9)
                      + ((((k2 >> 3) & 3) * 16 + (n & 15)) << 3) + (k2 & 7);
        s_w1Hi[off] = h; s_w1Lo[off] = l;
    }
    // biasq + per-feature consts
    if (tid < H0) {
        float acc = b0[tid];
        #pragma unroll 8
        for (int d = 0; d < D; ++d)
            acc = fmaf(qb[d], W0[d * H0 + tid] + W0[(128 + d) * H0 + tid], acc);
        s_biasq[tid] = acc;
        s_a0[tid]    = a0[tid];
    }
    if (tid < 48) {
        s_b1p[tid] = (tid < H1) ? b1[tid] : 0.0f;
        s_a1p[tid] = (tid < H1) ? a1[tid] : 0.0f;
        s_Wop[tid] = (tid < H1) ? Wo[tid] : 0.0f;
    }
    __syncthreads();

    // ---- Phase 1: per-wave M-tiles with k prefetch ----
    for (int mt = wv; mt < 13; mt += 4) {
        float4 kn[4];
        const bool hasNext = (mt + 4 < 13);
        if (hasNext) {
            int row = (mt + 4) * 16 + l16; if (row > T - 1) row = T - 1;
            const float* kr = k + ((size_t)b * T + row) * D + quad * 8;
            kn[0] = *(const float4*)(kr);
            kn[1] = *(const float4*)(kr + 4);
            kn[2] = *(const float4*)(kr + 32);
            kn[3] = *(const float4*)(kr + 36);
        }
        // A1 fragments from current k tile (split bf16)
        short8 a1hi[2], a1lo[2];
        #pragma unroll
        for (int ks = 0; ks < 2; ++ks) {
            float xs[8] = {kc[ks*2].x, kc[ks*2].y, kc[ks*2].z, kc[ks*2].w,
                           kc[ks*2+1].x, kc[ks*2+1].y, kc[ks*2+1].z, kc[ks*2+1].w};
            #pragma unroll
            for (int j = 0; j < 8; ++j) {
                unsigned short h, l; split_bf16(xs[j], h, l);
                a1hi[ks][j] = (short)h; a1lo[ks][j] = (short)l;
            }
        }
        // Layer 1: 5 N-tiles, fully unrolled -> 5 independent MFMA chains
        #pragma unroll
        for (int nt = 0; nt < 5; ++nt) {
            f32x4 acc = {0.0f, 0.0f, 0.0f, 0.0f};
            #pragma unroll
            for (int ks = 0; ks < 2; ++ks) {
                const int off = (ks * 5 + nt) * 512 + lane * 8;
                short8 bh = *(const short8*)&s_wfHi[off];
                short8 bl = *(const short8*)&s_wfLo[off];
                acc = __builtin_amdgcn_mfma_f32_16x16x32_bf16(a1hi[ks], bh, acc, 0, 0, 0);
                acc = __builtin_amdgcn_mfma_f32_16x16x32_bf16(a1hi[ks], bl, acc, 0, 0, 0);
                acc = __builtin_amdgcn_mfma_f32_16x16x32_bf16(a1lo[ks], bh, acc, 0, 0, 0);
            }
            const int h = nt * 16 + l16;
            const float bq = s_biasq[h], al = s_a0[h];
            #pragma unroll
            for (int reg = 0; reg < 4; ++reg) {
                const float x   = acc[reg] + bq;
                const float h0v = (x >= 0.0f) ? x : al * x;
                unsigned short hh, hl; split_bf16(h0v, hh, hl);
                const int addr = (quad * 4 + reg) * 80 + h;
                s_h0hi[wv][addr] = hh;
                s_h0lo[wv][addr] = hl;
            }
        }
        __asm__ __volatile__("s_waitcnt lgkmcnt(0)" ::: "memory");

        // Layer 2 A-fragments from LDS; k2 in [80,96) -> zero frags
        short8 a2hi[3], a2lo[3];
        #pragma unroll
        for (int k2s = 0; k2s < 3; ++k2s) {
            if (k2s < 2 || quad < 2) {
                const int addr = l16 * 80 + k2s * 32 + quad * 8;
                a2hi[k2s] = *(const short8*)&s_h0hi[wv][addr];
                a2lo[k2s] = *(const short8*)&s_h0lo[wv][addr];
            } else {
                short8 z = {0, 0, 0, 0, 0, 0, 0, 0};
                a2hi[k2s] = z; a2lo[k2s] = z;
            }
        }
        float part[4] = {0.0f, 0.0f, 0.0f, 0.0f};
        #pragma unroll
        for (int nt2 = 0; nt2 < 3; ++nt2) {
            f32x4 acc = {0.0f, 0.0f, 0.0f, 0.0f};
            #pragma unroll
            for (int k2s = 0; k2s < 3; ++k2s) {
                const int off = (k2s * 3 + nt2) * 512 + lane * 8;
                short8 bh = *(const short8*)&s_w1Hi[off];
                short8 bl = *(const short8*)&s_w1Lo[off];
                acc = __builtin_amdgcn_mfma_f32_16x16x32_bf16(a2hi[k2s], bh, acc, 0, 0, 0);
                acc = __builtin_amdgcn_mfma_f32_16x16x32_bf16(a2hi[k2s], bl, acc, 0, 0, 0);
                acc = __builtin_amdgcn_mfma_f32_16x16x32_bf16(a2lo[k2s], bh, acc, 0, 0, 0);
            }
            const int g = nt2 * 16 + l16;
            const float bg = s_b1p[g], ag = s_a1p[g], wg = s_Wop[g];
            #pragma unroll
            for (int reg = 0; reg < 4; ++reg) {
                const float x  = acc[reg] + bg;
                const float hv = (x >= 0.0f) ? x : ag * x;
                part[reg] = fmaf(hv, wg, part[reg]);
            }
        }
        // reduce over the 16 cols (lane bits 0..3)
        #pragma unroll
        for (int off = 1; off < 16; off <<= 1) {
            #pragma unroll
            for (int reg = 0; reg < 4; ++reg)
                part[reg] += __shfl_xor(part[reg], off);
        }
        if (l16 == 0) {
            float4 p = {part[0], part[1], part[2], part[3]};
            *(float4*)&s_logits[mt * 16 + quad * 4] = p;
        }
        if (hasNext) {
            #pragma unroll
            for (int i = 0; i < 4; ++i) kc[i] = kn[i];
        }
    }
    __asm__ __volatile__("s_waitcnt lgkmcnt(0)" ::: "memory");
    __syncthreads();

    // ---- Phase 2: mask + softmax over T (pads -> -inf => exp 0) ----
    float logit = -INFINITY;
    if (tid < T)
        logit = (mval == 0) ? NEG_INF_V : s_logits[tid];

    float m = logit;
    #pragma unroll
    for (int off = 32; off > 0; off >>= 1) m = fmaxf(m, __shfl_xor(m, off));
    if (lane == 0) s_red[wv] = m;
    __syncthreads();
    m = fmaxf(fmaxf(s_red[0], s_red[1]), fmaxf(s_red[2], s_red[3]));
    const float e = expf(logit - m);
    s_w[tid] = e;
    float ssum = e;
    #pragma unroll
    for (int off = 32; off > 0; off >>= 1) ssum += __shfl_xor(ssum, off);
    if (lane == 0) s_red[4 + wv] = ssum;
    __syncthreads();
    const float inv = 1.0f / (s_red[4] + s_red[5] + s_red[6] + s_red[7]);

    // ---- out[b,d] = sum_t w_t * v[b,t,d] (coalesced in d) ----
    const int d = tid & (D - 1);
    const int c = tid >> 6;
    constexpr int TC = T / 4;          // 50
    float acc2 = 0.0f;
    const float* vp = v + ((size_t)b * T + c * TC) * D + d;
    #pragma unroll 10
    for (int t = 0; t < TC; ++t)
        acc2 = fmaf(s_w[c * TC + t], vp[t * D], acc2);
    s_part[c][d] = acc2;
    __syncthreads();
    if (tid < D) {
        out[(size_t)b * D + tid] =
            (s_part[0][tid] + s_part[1][tid] + s_part[2][tid] + s_part[3][tid]) * inv;
    }
}

extern "C" void kernel_launch(void* const* d_in, const int* in_sizes, int n_in,
                              void* d_out, int out_size, void* d_ws, size_t ws_size,
                              hipStream_t stream) {
    const float* q  = (const float*)d_in[0];
    const float* k  = (const float*)d_in[1];
    const float* v  = (const float*)d_in[2];
    const float* W0 = (const float*)d_in[3];
    const float* b0 = (const float*)d_in[4];
    const float* a0 = (const float*)d_in[5];
    const float* W1 = (const float*)d_in[6];
    const float* b1 = (const float*)d_in[7];
    const float* a1 = (const float*)d_in[8];
    const float* Wo = (const float*)d_in[9];
    const int*  mask = (const int*)d_in[11];
    float* out = (float*)d_out;

    const int B = in_sizes[0] / D;            // 2048

    attn_fused<<<dim3(B), dim3(BLOCK), 0, stream>>>(
        q, k, v, W0, b0, a0, W1, b1, a1, Wo, mask, out);
}